// Round 2
// baseline (416.946 us; speedup 1.0000x reference)
//
#include <hip/hip_runtime.h>
#include <math.h>

#define CIN 8
#define HIN 128
#define WIN 128
#define OH 126
#define OW 126
#define COUT 64
#define NB 128
#define NGROUPS 16
#define CPG 4
#define PWN 31
#define CT 16          // out-channel tile
#define TS 32          // spatial tile

// workspace layout (floats)
#define NPOOL (NB*COUT*PWN*PWN)          // 7,872,512
#define OFF_WMAX 0
#define OFF_WMIN (NPOOL)
#define OFF_PART (2*NPOOL)               // [b][g][tile16][{sum,sumsq}]
#define NPART (NB*NGROUPS*16*2)
#define OFF_STATS (OFF_PART + NPART)     // [b*16+g][{mean,inv}]

__global__ __launch_bounds__(256, 2)
void conv_stats_pool_kernel(const float* __restrict__ x,
                            const float* __restrict__ w,
                            const float* __restrict__ bias,
                            float* __restrict__ ws)
{
  __shared__ float xs[CIN][34][36];   // stride 36 to soften bank conflicts
  __shared__ float red[4][8];

  const int tid = threadIdx.x;
  const int tileIdx = blockIdx.x;      // 0..15
  const int tx = tileIdx & 3, ty = tileIdx >> 2;
  const int ct = blockIdx.y;           // 0..3
  const int b  = blockIdx.z;

  const int ox0 = tx * TS, oy0 = ty * TS;

  // ---- stage input tile (8 x 34 x 34) into LDS ----
  const float* xb = x + (size_t)b * CIN * HIN * WIN;
  for (int idx = tid; idx < CIN*34*34; idx += 256) {
    int ci = idx / (34*34);
    int r  = (idx / 34) % 34;
    int c  = idx % 34;
    int iy = oy0 + r, ix = ox0 + c;
    float v = 0.f;
    if (iy < HIN && ix < WIN) v = xb[(ci*HIN + iy)*WIN + ix];
    xs[ci][r][c] = v;
  }
  __syncthreads();

  const int row  = tid >> 3;   // 0..31
  const int cg   = tid & 7;    // 0..7
  const int col0 = cg * 4;     // window-aligned 4-pixel run

  float acc[CT][4];
  #pragma unroll
  for (int co = 0; co < CT; ++co)
    #pragma unroll
    for (int i = 0; i < 4; ++i) acc[co][i] = 0.f;

  const float* wbase = w + (size_t)ct * CT * CIN * 9;   // block-uniform -> s_load weights

  #pragma unroll 1
  for (int ci = 0; ci < CIN; ++ci) {
    float p[3][6];
    #pragma unroll
    for (int ky = 0; ky < 3; ++ky)
      #pragma unroll
      for (int k = 0; k < 6; ++k)
        p[ky][k] = xs[ci][row + ky][col0 + k];
    #pragma unroll
    for (int co = 0; co < CT; ++co) {
      const float* wp = wbase + (co*CIN + ci)*9;
      #pragma unroll
      for (int ky = 0; ky < 3; ++ky)
        #pragma unroll
        for (int kx = 0; kx < 3; ++kx) {
          const float wv = wp[ky*3+kx];      // uniform -> SGPR operand of v_fmac
          #pragma unroll
          for (int i = 0; i < 4; ++i)
            acc[co][i] = fmaf(wv, p[ky][kx+i], acc[co][i]);
        }
    }
  }

  // bias (before stats: GN sees y+bias)
  #pragma unroll
  for (int co = 0; co < CT; ++co) {
    const float bv = bias[ct*CT + co];
    #pragma unroll
    for (int i = 0; i < 4; ++i) acc[co][i] += bv;
  }

  const int  oy = oy0 + row;
  const bool rowValid = (oy < OH);

  // ---- group stats partials (4 groups in this channel tile) ----
  float s[4]  = {0,0,0,0};
  float sq[4] = {0,0,0,0};
  #pragma unroll
  for (int co = 0; co < CT; ++co) {
    const int gl = co >> 2;
    #pragma unroll
    for (int i = 0; i < 4; ++i) {
      const bool ok = rowValid && (ox0 + col0 + i < OW);
      const float val = ok ? acc[co][i] : 0.f;
      s[gl]  += val;
      sq[gl] += val * val;
    }
  }
  // vals layout: {s0,s1,s2,s3,sq0,sq1,sq2,sq3}
  float vals[8];
  #pragma unroll
  for (int k = 0; k < 4; ++k) { vals[k] = s[k]; vals[4+k] = sq[k]; }
  #pragma unroll
  for (int k = 0; k < 8; ++k) {
    float v = vals[k];
    #pragma unroll
    for (int off = 1; off < 64; off <<= 1)
      v += __shfl_xor(v, off, 64);
    vals[k] = v;
  }
  const int wave = tid >> 6;
  if ((tid & 63) == 0) {
    #pragma unroll
    for (int k = 0; k < 8; ++k) red[wave][k] = vals[k];
  }
  __syncthreads();
  if (tid < 8) {
    const float t = red[0][tid] + red[1][tid] + red[2][tid] + red[3][tid];
    // FIX (R1): vals layout is planar {s0..s3, sq0..sq3}:
    //   kind = tid>>2 (0=sum,1=sumsq), gl = tid&3.  (was gl=tid>>1,kind=tid&1)
    const int kind = tid >> 2;
    const int gl   = tid & 3;
    const int g    = ct * 4 + gl;
    ws[OFF_PART + (((size_t)b*NGROUPS + g)*16 + tileIdx)*2 + kind] = t;
  }

  // ---- 4x4 window max/min (thread's 4 cols are one window-col group) ----
  const int wy  = oy >> 2;              // 8*ty + row/4
  const int wxg = (ox0 + col0) >> 2;    // 8*tx + cg
  const bool winValid = (wy < PWN) && (wxg < PWN);
  float* wmax = ws + OFF_WMAX;
  float* wmin = ws + OFF_WMIN;
  #pragma unroll
  for (int co = 0; co < CT; ++co) {
    float mx = fmaxf(fmaxf(acc[co][0], acc[co][1]), fmaxf(acc[co][2], acc[co][3]));
    float mn = fminf(fminf(acc[co][0], acc[co][1]), fminf(acc[co][2], acc[co][3]));
    mx = fmaxf(mx, __shfl_xor(mx, 8, 64));   // lane bit3 = row bit0
    mx = fmaxf(mx, __shfl_xor(mx, 16, 64));  // lane bit4 = row bit1
    mn = fminf(mn, __shfl_xor(mn, 8, 64));
    mn = fminf(mn, __shfl_xor(mn, 16, 64));
    if (winValid && ((row & 3) == 0)) {
      const int c = ct*CT + co;
      const size_t o = (((size_t)b*COUT + c)*PWN + wy)*PWN + wxg;
      wmax[o] = mx;
      wmin[o] = mn;
    }
  }
}

__global__ void stats_kernel(float* __restrict__ ws)
{
  const int g = blockIdx.x * blockDim.x + threadIdx.x;   // 0..2047
  if (g >= NB*NGROUPS) return;
  float s = 0.f, sq = 0.f;
  const float* p = ws + OFF_PART + (size_t)g * 16 * 2;
  #pragma unroll
  for (int t = 0; t < 16; ++t) { s += p[t*2]; sq += p[t*2+1]; }
  const float N = (float)(CPG * OH * OW);
  const float mean = s / N;
  const float var  = sq / N - mean * mean;
  const float inv  = rsqrtf(var + 1e-5f);
  ws[OFF_STATS + g*2]     = mean;
  ws[OFF_STATS + g*2 + 1] = inv;
}

__global__ void final_kernel(const float* __restrict__ gnw,
                             const float* __restrict__ gnb,
                             const float* __restrict__ scale,
                             const float* __restrict__ ws,
                             float* __restrict__ out)
{
  const int idx = blockIdx.x * 256 + threadIdx.x;
  if (idx >= NPOOL) return;
  const int bc = idx / (PWN*PWN);
  const int c  = bc % COUT;
  const int b  = bc / COUT;
  const int g  = c >> 2;
  const float mean = ws[OFF_STATS + (b*NGROUPS + g)*2];
  const float inv  = ws[OFF_STATS + (b*NGROUPS + g)*2 + 1];
  const float A  = inv * gnw[c] * scale[c];
  const float Bt = (gnb[c] - mean * inv * gnw[c]) * scale[c];
  const float mx = ws[OFF_WMAX + idx];
  const float mn = ws[OFF_WMIN + idx];
  float v = (A >= 0.f) ? fmaf(A, mx, Bt) : fmaf(A, mn, Bt);
  v = fminf(fmaxf(v, 0.f), 1.f);
  out[idx] = v;
}

extern "C" void kernel_launch(void* const* d_in, const int* in_sizes, int n_in,
                              void* d_out, int out_size, void* d_ws, size_t ws_size,
                              hipStream_t stream)
{
  const float* x     = (const float*)d_in[0];
  const float* cw    = (const float*)d_in[1];
  const float* cb    = (const float*)d_in[2];
  const float* gnw   = (const float*)d_in[3];
  const float* gnb   = (const float*)d_in[4];
  const float* scale = (const float*)d_in[5];
  float* out = (float*)d_out;
  float* ws  = (float*)d_ws;

  dim3 gridA(16, 4, NB);
  conv_stats_pool_kernel<<<gridA, 256, 0, stream>>>(x, cw, cb, ws);

  stats_kernel<<<(NB*NGROUPS + 255)/256, 256, 0, stream>>>(ws);

  final_kernel<<<(NPOOL + 255)/256, 256, 0, stream>>>(gnw, gnb, scale, ws, out);
}

// Round 3
// 316.860 us; speedup vs baseline: 1.3159x; 1.3159x over previous
//
#include <hip/hip_runtime.h>
#include <math.h>

typedef _Float16 f16x8 __attribute__((ext_vector_type(8)));
typedef float f32x4 __attribute__((ext_vector_type(4)));

#define CIN 8
#define HIN 128
#define WIN 128
#define OH 126
#define OW 126
#define COUT 64
#define NB 128
#define NGROUPS 16
#define CPG 4
#define PWN 31

// workspace layout (floats) — same as R2 (stats_kernel/final_kernel compatible)
#define NPOOL (NB*COUT*PWN*PWN)          // 7,872,512
#define OFF_WMAX 0
#define OFF_WMIN (NPOOL)
#define OFF_PART (2*NPOOL)               // [b][g][tile16][{sum,sumsq}]
#define NPART (NB*NGROUPS*16*2)
#define OFF_STATS (OFF_PART + NPART)     // [b*16+g][{mean,inv}]

// Conv via MFMA implicit GEMM.
// K ordering: k = khw*8 + ci  (khw = ky*3+kx, padded 9..11 with W=0)
// LDS x tile: [row 37][col 34][ci 8] f16  (rows 34..36 only feed W=0 taps; staged finite)
// LDS w:      [khw 12][n 64][ci 8] f16
// M-tile = one 4x4 pool window: C row = pixel (y=wy*4+quad, x=wx*4+reg), col = channel.
__global__ __launch_bounds__(256, 4)
void conv_mfma_kernel(const float* __restrict__ x,
                      const float* __restrict__ w,
                      const float* __restrict__ bias,
                      float* __restrict__ ws)
{
  __shared__ __align__(16) _Float16 xs[37*34*8];   // 20,128 B
  __shared__ __align__(16) _Float16 wls[12*64*8];  // 12,288 B
  __shared__ float red[4][16][2];

  const int tid  = threadIdx.x;
  const int lane = tid & 63, wave = tid >> 6;
  const int tileIdx = blockIdx.x;          // 0..15
  const int tx = tileIdx & 3, ty = tileIdx >> 2;
  const int b  = blockIdx.y;
  const int ox0 = tx*32, oy0 = ty*32;

  // ---- stage weights [khw][n][ci], khw>=9 zeroed (kills padded-K taps) ----
  for (int idx = tid; idx < 12*64*8; idx += 256) {
    const int ci = idx & 7, n = (idx >> 3) & 63, khw = idx >> 9;
    const float v = (khw < 9) ? w[(n*CIN + ci)*9 + khw] : 0.f;
    wls[idx] = (_Float16)v;
  }

  // ---- stage x tile [37][34][ci] as f16 (pairs packed to 4B ds_writes) ----
  const float* xb = x + (size_t)b * CIN*HIN*WIN;
  for (int p = tid; p < 37*34; p += 256) {
    const int r = p / 34, c = p - r*34;
    const int iy = oy0 + r, ix = ox0 + c;
    const bool ok = (iy < HIN) && (ix < WIN);
    const int gbase = iy*WIN + ix;
    #pragma unroll
    for (int ci = 0; ci < 8; ci += 2) {
      const float v0 = ok ? xb[ci*HIN*WIN + gbase] : 0.f;
      const float v1 = ok ? xb[(ci+1)*HIN*WIN + gbase] : 0.f;
      union { _Float16 h[2]; unsigned int u; } pk;
      pk.h[0] = (_Float16)v0; pk.h[1] = (_Float16)v1;
      *(unsigned int*)&xs[p*8 + ci] = pk.u;
    }
  }
  __syncthreads();

  const int q = lane >> 4, ln = lane & 15;

  // B fragments: 4 channel-tiles x 3 K-chunks, resident in VGPRs (48)
  f16x8 bf[4][3];
  #pragma unroll
  for (int nt = 0; nt < 4; ++nt)
    #pragma unroll
    for (int c = 0; c < 3; ++c)
      bf[nt][c] = *(const f16x8*)&wls[((c*4 + q)*64 + nt*16 + ln)*8];

  // per-lane A offsets: A-frag lane map: m = lane&15 (pixel), k-quad = lane>>4
  const int dy = ln >> 2, dx = ln & 3;
  int aoff[3];
  #pragma unroll
  for (int c = 0; c < 3; ++c) {
    const int khw = c*4 + q;               // 0..11
    const int ky = khw / 3, kx = khw - 3*(khw/3);
    aoff[c] = ((dy + ky)*34 + (dx + kx))*8;   // f16 elements
  }

  float bias_r[4];
  #pragma unroll
  for (int nt = 0; nt < 4; ++nt) bias_r[nt] = bias[nt*16 + ln];

  float s[4]  = {0.f,0.f,0.f,0.f};
  float sq[4] = {0.f,0.f,0.f,0.f};
  float* wmax = ws + OFF_WMAX;
  float* wmin = ws + OFF_WMIN;

  // 16 pool windows per wave (2 window-rows x 8 cols)
  #pragma unroll 2
  for (int i = 0; i < 16; ++i) {
    const int wyl = wave*2 + (i >> 3), wxl = i & 7;
    const int base = (wyl*4*34 + wxl*4)*8;

    f32x4 acc[4];
    #pragma unroll
    for (int nt = 0; nt < 4; ++nt) acc[nt] = (f32x4){0.f,0.f,0.f,0.f};
    #pragma unroll
    for (int c = 0; c < 3; ++c) {
      const f16x8 a = *(const f16x8*)&xs[base + aoff[c]];
      #pragma unroll
      for (int nt = 0; nt < 4; ++nt)
        acc[nt] = __builtin_amdgcn_mfma_f32_16x16x32_f16(a, bf[nt][c], acc[nt], 0, 0, 0);
    }

    const int wyg = ty*8 + wyl, wxg = tx*8 + wxl;
    const int ylane = wyg*4 + q;                 // this lane's pixel row
    if ((wyg < PWN) && (wxg < PWN)) {
      // fully-valid window: stats + pool
      #pragma unroll
      for (int nt = 0; nt < 4; ++nt) {
        const float bv = bias_r[nt];
        const float v0 = acc[nt][0]+bv, v1 = acc[nt][1]+bv;
        const float v2 = acc[nt][2]+bv, v3 = acc[nt][3]+bv;
        s[nt]  += (v0+v1) + (v2+v3);
        sq[nt] += v0*v0 + v1*v1 + v2*v2 + v3*v3;
        float mx = fmaxf(fmaxf(v0,v1), fmaxf(v2,v3));
        float mn = fminf(fminf(v0,v1), fminf(v2,v3));
        mx = fmaxf(mx, __shfl_xor(mx, 16, 64));
        mx = fmaxf(mx, __shfl_xor(mx, 32, 64));
        mn = fminf(mn, __shfl_xor(mn, 16, 64));
        mn = fminf(mn, __shfl_xor(mn, 32, 64));
        if (lane < 16) {
          const size_t o = (((size_t)b*COUT + nt*16 + ln)*PWN + wyg)*PWN + wxg;
          wmax[o] = mx; wmin[o] = mn;
        }
      }
    } else {
      // edge tile: stats only, per-pixel masked (y<126, x<126)
      const bool yv = ylane < OH;
      #pragma unroll
      for (int nt = 0; nt < 4; ++nt) {
        const float bv = bias_r[nt];
        #pragma unroll
        for (int r = 0; r < 4; ++r) {
          const bool okp = yv && (wxg*4 + r < OW);
          const float v = okp ? (acc[nt][r] + bv) : 0.f;
          s[nt] += v; sq[nt] += v*v;
        }
      }
    }
  }

  // per-wave stat reduce: quads (xor 16,32) then channels-in-group (xor 1,2)
  #pragma unroll
  for (int nt = 0; nt < 4; ++nt) {
    float a = s[nt], c2 = sq[nt];
    a  += __shfl_xor(a, 16, 64);  a  += __shfl_xor(a, 32, 64);
    a  += __shfl_xor(a, 1, 64);   a  += __shfl_xor(a, 2, 64);
    c2 += __shfl_xor(c2, 16, 64); c2 += __shfl_xor(c2, 32, 64);
    c2 += __shfl_xor(c2, 1, 64);  c2 += __shfl_xor(c2, 2, 64);
    if (lane < 16 && (lane & 3) == 0) {
      red[wave][nt*4 + (ln >> 2)][0] = a;
      red[wave][nt*4 + (ln >> 2)][1] = c2;
    }
  }
  __syncthreads();
  if (tid < 32) {
    const int g = tid >> 1, k = tid & 1;
    const float t = red[0][g][k] + red[1][g][k] + red[2][g][k] + red[3][g][k];
    ws[OFF_PART + (((size_t)b*NGROUPS + g)*16 + tileIdx)*2 + k] = t;
  }
}

__global__ void stats_kernel(float* __restrict__ ws)
{
  const int g = blockIdx.x * blockDim.x + threadIdx.x;   // 0..2047
  if (g >= NB*NGROUPS) return;
  float s = 0.f, sq = 0.f;
  const float* p = ws + OFF_PART + (size_t)g * 16 * 2;
  #pragma unroll
  for (int t = 0; t < 16; ++t) { s += p[t*2]; sq += p[t*2+1]; }
  const float N = (float)(CPG * OH * OW);
  const float mean = s / N;
  const float var  = sq / N - mean * mean;
  const float inv  = rsqrtf(var + 1e-5f);
  ws[OFF_STATS + g*2]     = mean;
  ws[OFF_STATS + g*2 + 1] = inv;
}

__global__ void final_kernel(const float* __restrict__ gnw,
                             const float* __restrict__ gnb,
                             const float* __restrict__ scale,
                             const float* __restrict__ ws,
                             float* __restrict__ out)
{
  const int idx = blockIdx.x * 256 + threadIdx.x;
  if (idx >= NPOOL) return;
  const int bc = idx / (PWN*PWN);
  const int c  = bc % COUT;
  const int b  = bc / COUT;
  const int g  = c >> 2;
  const float mean = ws[OFF_STATS + (b*NGROUPS + g)*2];
  const float inv  = ws[OFF_STATS + (b*NGROUPS + g)*2 + 1];
  const float A  = inv * gnw[c] * scale[c];
  const float Bt = (gnb[c] - mean * inv * gnw[c]) * scale[c];
  const float mx = ws[OFF_WMAX + idx];
  const float mn = ws[OFF_WMIN + idx];
  float v = (A >= 0.f) ? fmaf(A, mx, Bt) : fmaf(A, mn, Bt);
  v = fminf(fmaxf(v, 0.f), 1.f);
  out[idx] = v;
}

extern "C" void kernel_launch(void* const* d_in, const int* in_sizes, int n_in,
                              void* d_out, int out_size, void* d_ws, size_t ws_size,
                              hipStream_t stream)
{
  const float* x     = (const float*)d_in[0];
  const float* cw    = (const float*)d_in[1];
  const float* cb    = (const float*)d_in[2];
  const float* gnw   = (const float*)d_in[3];
  const float* gnb   = (const float*)d_in[4];
  const float* scale = (const float*)d_in[5];
  float* out = (float*)d_out;
  float* ws  = (float*)d_ws;

  dim3 gridA(16, NB, 1);
  conv_mfma_kernel<<<gridA, 256, 0, stream>>>(x, cw, cb, ws);

  stats_kernel<<<(NB*NGROUPS + 255)/256, 256, 0, stream>>>(ws);

  final_kernel<<<(NPOOL + 255)/256, 256, 0, stream>>>(gnw, gnb, scale, ws, out);
}

// Round 4
// 204.729 us; speedup vs baseline: 2.0366x; 1.5477x over previous
//
#include <hip/hip_runtime.h>
#include <math.h>

typedef _Float16 f16x8 __attribute__((ext_vector_type(8)));
typedef float f32x4 __attribute__((ext_vector_type(4)));

#define CIN 8
#define HIN 128
#define WIN 128
#define OH 126
#define OW 126
#define COUT 64
#define NB 128
#define NGROUPS 16
#define CPG 4
#define PWN 31

// workspace layout (floats)
// pool extrema now channel-innermost: [b][wy][wx][c]  (c innermost => coalesced
// 64B-line stores from the 16 active lanes; R3's NCHW layout caused 7x write
// amplification: 447MB WRITE_SIZE from 4B-per-line scatter)
#define NPOOL (NB*PWN*PWN*COUT)          // 7,872,512
#define OFF_WMAX 0
#define OFF_WMIN (NPOOL)
#define OFF_PART (2*NPOOL)               // [b][g][tile16][{sum,sumsq}]
#define NPART (NB*NGROUPS*16*2)
#define OFF_STATS (OFF_PART + NPART)     // [b*16+g][{mean,inv}]

// Conv via MFMA implicit GEMM.
// K ordering: k = khw*8 + ci  (khw = ky*3+kx, padded 9..11 with W=0)
// LDS x tile: [row 37][col 34][ci 8] f16  (rows 34..36 only feed W=0 taps)
// LDS w:      [khw 12][n 64][ci 8] f16
// M-tile = one 4x4 pool window: C row = pixel (y=wy*4+quad, x=wx*4+reg), col = channel.
__global__ __launch_bounds__(256, 4)
void conv_mfma_kernel(const float* __restrict__ x,
                      const float* __restrict__ w,
                      const float* __restrict__ bias,
                      float* __restrict__ ws)
{
  __shared__ __align__(16) _Float16 xs[37*34*8];   // 20,128 B
  __shared__ __align__(16) _Float16 wls[12*64*8];  // 12,288 B
  __shared__ float red[4][16][2];

  const int tid  = threadIdx.x;
  const int lane = tid & 63, wave = tid >> 6;
  const int tileIdx = blockIdx.x;          // 0..15
  const int tx = tileIdx & 3, ty = tileIdx >> 2;
  const int b  = blockIdx.y;
  const int ox0 = tx*32, oy0 = ty*32;

  // ---- stage weights [khw][n][ci], khw>=9 zeroed (kills padded-K taps) ----
  for (int idx = tid; idx < 12*64*8; idx += 256) {
    const int ci = idx & 7, n = (idx >> 3) & 63, khw = idx >> 9;
    const float v = (khw < 9) ? w[(n*CIN + ci)*9 + khw] : 0.f;
    wls[idx] = (_Float16)v;
  }

  // ---- stage x tile [37][34][ci] as f16 (pairs packed to 4B ds_writes) ----
  const float* xb = x + (size_t)b * CIN*HIN*WIN;
  for (int p = tid; p < 37*34; p += 256) {
    const int r = p / 34, c = p - r*34;
    const int iy = oy0 + r, ix = ox0 + c;
    const bool ok = (iy < HIN) && (ix < WIN);
    const int gbase = iy*WIN + ix;
    #pragma unroll
    for (int ci = 0; ci < 8; ci += 2) {
      const float v0 = ok ? xb[ci*HIN*WIN + gbase] : 0.f;
      const float v1 = ok ? xb[(ci+1)*HIN*WIN + gbase] : 0.f;
      union { _Float16 h[2]; unsigned int u; } pk;
      pk.h[0] = (_Float16)v0; pk.h[1] = (_Float16)v1;
      *(unsigned int*)&xs[p*8 + ci] = pk.u;
    }
  }
  __syncthreads();

  const int q = lane >> 4, ln = lane & 15;

  // B fragments: 4 channel-tiles x 3 K-chunks, resident in VGPRs (48)
  f16x8 bf[4][3];
  #pragma unroll
  for (int nt = 0; nt < 4; ++nt)
    #pragma unroll
    for (int c = 0; c < 3; ++c)
      bf[nt][c] = *(const f16x8*)&wls[((c*4 + q)*64 + nt*16 + ln)*8];

  // per-lane A offsets: A-frag lane map: m = lane&15 (pixel), k-quad = lane>>4
  const int dy = ln >> 2, dx = ln & 3;
  int aoff[3];
  #pragma unroll
  for (int c = 0; c < 3; ++c) {
    const int khw = c*4 + q;               // 0..11
    const int ky = khw / 3, kx = khw - 3*(khw/3);
    aoff[c] = ((dy + ky)*34 + (dx + kx))*8;   // f16 elements
  }

  float bias_r[4];
  #pragma unroll
  for (int nt = 0; nt < 4; ++nt) bias_r[nt] = bias[nt*16 + ln];

  float s[4]  = {0.f,0.f,0.f,0.f};
  float sq[4] = {0.f,0.f,0.f,0.f};
  float* wmax = ws + OFF_WMAX;
  float* wmin = ws + OFF_WMIN;

  // 16 pool windows per wave (2 window-rows x 8 cols)
  #pragma unroll 2
  for (int i = 0; i < 16; ++i) {
    const int wyl = wave*2 + (i >> 3), wxl = i & 7;
    const int base = (wyl*4*34 + wxl*4)*8;

    f32x4 acc[4];
    #pragma unroll
    for (int nt = 0; nt < 4; ++nt) acc[nt] = (f32x4){0.f,0.f,0.f,0.f};
    #pragma unroll
    for (int c = 0; c < 3; ++c) {
      const f16x8 a = *(const f16x8*)&xs[base + aoff[c]];
      #pragma unroll
      for (int nt = 0; nt < 4; ++nt)
        acc[nt] = __builtin_amdgcn_mfma_f32_16x16x32_f16(a, bf[nt][c], acc[nt], 0, 0, 0);
    }

    const int wyg = ty*8 + wyl, wxg = tx*8 + wxl;
    const int ylane = wyg*4 + q;                 // this lane's pixel row
    if ((wyg < PWN) && (wxg < PWN)) {
      // fully-valid window: stats + pool
      const size_t rowbase = ((size_t)(b*PWN + wyg)*PWN + wxg)*COUT;  // c-innermost
      #pragma unroll
      for (int nt = 0; nt < 4; ++nt) {
        const float bv = bias_r[nt];
        const float v0 = acc[nt][0]+bv, v1 = acc[nt][1]+bv;
        const float v2 = acc[nt][2]+bv, v3 = acc[nt][3]+bv;
        s[nt]  += (v0+v1) + (v2+v3);
        sq[nt] += v0*v0 + v1*v1 + v2*v2 + v3*v3;
        float mx = fmaxf(fmaxf(v0,v1), fmaxf(v2,v3));
        float mn = fminf(fminf(v0,v1), fminf(v2,v3));
        mx = fmaxf(mx, __shfl_xor(mx, 16, 64));
        mx = fmaxf(mx, __shfl_xor(mx, 32, 64));
        mn = fminf(mn, __shfl_xor(mn, 16, 64));
        mn = fminf(mn, __shfl_xor(mn, 32, 64));
        if (lane < 16) {
          // lanes 0..15 write c = nt*16+ln -> one dense aligned 64B line
          const size_t o = rowbase + nt*16 + ln;
          wmax[o] = mx; wmin[o] = mn;
        }
      }
    } else {
      // edge tile: stats only, per-pixel masked (y<126, x<126)
      const bool yv = ylane < OH;
      #pragma unroll
      for (int nt = 0; nt < 4; ++nt) {
        const float bv = bias_r[nt];
        #pragma unroll
        for (int r = 0; r < 4; ++r) {
          const bool okp = yv && (wxg*4 + r < OW);
          const float v = okp ? (acc[nt][r] + bv) : 0.f;
          s[nt] += v; sq[nt] += v*v;
        }
      }
    }
  }

  // per-wave stat reduce: quads (xor 16,32) then channels-in-group (xor 1,2)
  #pragma unroll
  for (int nt = 0; nt < 4; ++nt) {
    float a = s[nt], c2 = sq[nt];
    a  += __shfl_xor(a, 16, 64);  a  += __shfl_xor(a, 32, 64);
    a  += __shfl_xor(a, 1, 64);   a  += __shfl_xor(a, 2, 64);
    c2 += __shfl_xor(c2, 16, 64); c2 += __shfl_xor(c2, 32, 64);
    c2 += __shfl_xor(c2, 1, 64);  c2 += __shfl_xor(c2, 2, 64);
    if (lane < 16 && (lane & 3) == 0) {
      red[wave][nt*4 + (ln >> 2)][0] = a;
      red[wave][nt*4 + (ln >> 2)][1] = c2;
    }
  }
  __syncthreads();
  if (tid < 32) {
    const int g = tid >> 1, k = tid & 1;
    const float t = red[0][g][k] + red[1][g][k] + red[2][g][k] + red[3][g][k];
    ws[OFF_PART + (((size_t)b*NGROUPS + g)*16 + tileIdx)*2 + k] = t;
  }
}

__global__ void stats_kernel(float* __restrict__ ws)
{
  const int g = blockIdx.x * blockDim.x + threadIdx.x;   // 0..2047
  if (g >= NB*NGROUPS) return;
  float s = 0.f, sq = 0.f;
  const float* p = ws + OFF_PART + (size_t)g * 16 * 2;
  #pragma unroll
  for (int t = 0; t < 16; ++t) { s += p[t*2]; sq += p[t*2+1]; }
  const float N = (float)(CPG * OH * OW);
  const float mean = s / N;
  const float var  = sq / N - mean * mean;
  const float inv  = rsqrtf(var + 1e-5f);
  ws[OFF_STATS + g*2]     = mean;
  ws[OFF_STATS + g*2 + 1] = inv;
}

// One block per (b, wy): read pool slab [wx][c] coalesced, affine+clamp,
// transpose through LDS, write NCHW rows (124B runs).
__global__ __launch_bounds__(256)
void final_kernel(const float* __restrict__ gnw,
                  const float* __restrict__ gnb,
                  const float* __restrict__ scale,
                  const float* __restrict__ ws,
                  float* __restrict__ out)
{
  __shared__ float As[COUT], Bs[COUT];
  __shared__ float vout[COUT*PWN];   // [c][wx], stride 31 -> conflict-free

  const int tid = threadIdx.x;
  const int wy  = blockIdx.x;   // 0..30
  const int b   = blockIdx.y;

  if (tid < COUT) {
    const int c = tid, g = c >> 2;
    const float mean = ws[OFF_STATS + (b*NGROUPS + g)*2];
    const float inv  = ws[OFF_STATS + (b*NGROUPS + g)*2 + 1];
    const float ag = inv * gnw[c];
    As[c] = ag * scale[c];
    Bs[c] = (gnb[c] - mean * ag) * scale[c];
  }
  __syncthreads();

  const size_t rb = (size_t)(b*PWN + wy)*PWN*COUT;
  for (int idx = tid; idx < PWN*COUT; idx += 256) {
    const int c = idx & 63, wx = idx >> 6;
    const float mx = ws[OFF_WMAX + rb + idx];
    const float mn = ws[OFF_WMIN + rb + idx];
    const float A = As[c], Bt = Bs[c];
    float v = (A >= 0.f) ? fmaf(A, mx, Bt) : fmaf(A, mn, Bt);
    v = fminf(fmaxf(v, 0.f), 1.f);
    vout[c*PWN + wx] = v;
  }
  __syncthreads();

  for (int idx = tid; idx < COUT*PWN; idx += 256) {
    const int c = idx / PWN, wx = idx - c*PWN;
    out[(((size_t)b*COUT + c)*PWN + wy)*PWN + wx] = vout[idx];
  }
}

extern "C" void kernel_launch(void* const* d_in, const int* in_sizes, int n_in,
                              void* d_out, int out_size, void* d_ws, size_t ws_size,
                              hipStream_t stream)
{
  const float* x     = (const float*)d_in[0];
  const float* cw    = (const float*)d_in[1];
  const float* cb    = (const float*)d_in[2];
  const float* gnw   = (const float*)d_in[3];
  const float* gnb   = (const float*)d_in[4];
  const float* scale = (const float*)d_in[5];
  float* out = (float*)d_out;
  float* ws  = (float*)d_ws;

  dim3 gridA(16, NB, 1);
  conv_mfma_kernel<<<gridA, 256, 0, stream>>>(x, cw, cb, ws);

  stats_kernel<<<(NB*NGROUPS + 255)/256, 256, 0, stream>>>(ws);

  dim3 gridF(PWN, NB, 1);
  final_kernel<<<gridF, 256, 0, stream>>>(gnw, gnb, scale, ws, out);
}

// Round 5
// 195.913 us; speedup vs baseline: 2.1282x; 1.0450x over previous
//
#include <hip/hip_runtime.h>
#include <math.h>

typedef _Float16 f16x8 __attribute__((ext_vector_type(8)));
typedef float f32x4 __attribute__((ext_vector_type(4)));

#define CIN 8
#define HIN 128
#define WIN 128
#define OH 126
#define OW 126
#define COUT 64
#define NB 128
#define NGROUPS 16
#define CPG 4
#define PWN 31
#define XROWS 35   // max row touched: base(28)+dy(3)+ky(3)=34

// workspace layout (floats)
// Single extremum plane [b][wy][wx][c] (c innermost, coalesced): conv stores
// max if gnw[c]*scale[c]>=0 else min — sign of GN affine slope is known
// pre-stats since inv_std>0. Halves pool traffic vs R4.
#define NPOOL (NB*PWN*PWN*COUT)          // 7,872,512
#define OFF_WEXT 0
#define OFF_PART (NPOOL)                 // [b][g][tile16][{sum,sumsq}]
#define NPART (NB*NGROUPS*16*2)

// Conv via MFMA implicit GEMM.
// K ordering: k = khw*8 + ci  (khw = ky*3+kx, padded 9..11 with W=0)
// LDS x tile: [row 35][col 34][ci 8] f16 ; staged as one ds_write_b128/pixel
// (R4 staged 4B at 16B lane-stride = 8-way bank conflict, 3.59M counted)
// LDS w:      [khw 12][n 64][ci 8] f16
// M-tile = one 4x4 pool window: C row = pixel, col = channel.
// Bias folded into MFMA C-operand init.
__global__ __launch_bounds__(256, 4)
void conv_mfma_kernel(const float* __restrict__ x,
                      const float* __restrict__ w,
                      const float* __restrict__ bias,
                      const float* __restrict__ gnw,
                      const float* __restrict__ scale,
                      float* __restrict__ ws)
{
  __shared__ __align__(16) _Float16 xs[XROWS*34*8];   // 19,040 B
  __shared__ __align__(16) _Float16 wls[12*64*8];     // 12,288 B
  __shared__ float red[4][16][2];

  const int tid  = threadIdx.x;
  const int lane = tid & 63, wave = tid >> 6;
  const int tileIdx = blockIdx.x;          // 0..15
  const int tx = tileIdx & 3, ty = tileIdx >> 2;
  const int b  = blockIdx.y;
  const int ox0 = tx*32, oy0 = ty*32;

  // ---- stage weights [khw][n][ci], khw>=9 zeroed ----
  for (int idx = tid; idx < 12*64*8; idx += 256) {
    const int ci = idx & 7, n = (idx >> 3) & 63, khw = idx >> 9;
    const float v = (khw < 9) ? w[(n*CIN + ci)*9 + khw] : 0.f;
    wls[idx] = (_Float16)v;
  }

  // ---- stage x tile: pack 8 ci -> one b128 write per pixel (conflict-free) ----
  const float* xb = x + (size_t)b * CIN*HIN*WIN;
  for (int p = tid; p < XROWS*34; p += 256) {
    const int r = p / 34, c = p - r*34;
    const int iy = oy0 + r, ix = ox0 + c;
    const bool ok = (iy < HIN) && (ix < WIN);
    const int gbase = iy*WIN + ix;
    f16x8 pk;
    #pragma unroll
    for (int ci = 0; ci < 8; ++ci) {
      const float v = ok ? xb[ci*HIN*WIN + gbase] : 0.f;
      pk[ci] = (_Float16)v;
    }
    *(f16x8*)&xs[p*8] = pk;
  }
  __syncthreads();

  const int q = lane >> 4, ln = lane & 15;

  // B fragments: 4 channel-tiles x 3 K-chunks resident (48 VGPRs)
  f16x8 bf[4][3];
  #pragma unroll
  for (int nt = 0; nt < 4; ++nt)
    #pragma unroll
    for (int c = 0; c < 3; ++c)
      bf[nt][c] = *(const f16x8*)&wls[((c*4 + q)*64 + nt*16 + ln)*8];

  // per-lane A offsets (A lane map: m = lane&15 pixel, k-quad = lane>>4)
  const int dy = ln >> 2, dx = ln & 3;
  int aoff[3];
  #pragma unroll
  for (int c = 0; c < 3; ++c) {
    const int khw = c*4 + q;
    const int ky = khw / 3, kx = khw - 3*(khw/3);
    aoff[c] = ((dy + ky)*34 + (dx + kx))*8;
  }

  float bias_r[4], sgn[4];
  #pragma unroll
  for (int nt = 0; nt < 4; ++nt) {
    const int c = nt*16 + ln;
    bias_r[nt] = bias[c];
    sgn[nt] = (gnw[c]*scale[c] >= 0.f) ? 1.f : -1.f;  // slope sign, inv>0
  }

  float s[4]  = {0.f,0.f,0.f,0.f};
  float sq[4] = {0.f,0.f,0.f,0.f};
  float* wext = ws + OFF_WEXT;

  // 16 pool windows per wave (2 window-rows x 8 cols)
  #pragma unroll 2
  for (int i = 0; i < 16; ++i) {
    const int wyl = wave*2 + (i >> 3), wxl = i & 7;
    const int base = (wyl*4*34 + wxl*4)*8;

    f32x4 acc[4];
    #pragma unroll
    for (int nt = 0; nt < 4; ++nt) {
      const float bv = bias_r[nt];
      acc[nt] = (f32x4){bv, bv, bv, bv};   // bias as MFMA C operand
    }
    #pragma unroll
    for (int c = 0; c < 3; ++c) {
      const f16x8 a = *(const f16x8*)&xs[base + aoff[c]];
      #pragma unroll
      for (int nt = 0; nt < 4; ++nt)
        acc[nt] = __builtin_amdgcn_mfma_f32_16x16x32_f16(a, bf[nt][c], acc[nt], 0, 0, 0);
    }

    const int wyg = ty*8 + wyl, wxg = tx*8 + wxl;
    if ((wyg < PWN) && (wxg < PWN)) {
      const size_t rowbase = ((size_t)(b*PWN + wyg)*PWN + wxg)*COUT;
      #pragma unroll
      for (int nt = 0; nt < 4; ++nt) {
        const float v0 = acc[nt][0], v1 = acc[nt][1];
        const float v2 = acc[nt][2], v3 = acc[nt][3];
        s[nt]  += (v0+v1) + (v2+v3);
        sq[nt] += v0*v0 + v1*v1 + v2*v2 + v3*v3;
        const float sg = sgn[nt];
        float m = fmaxf(fmaxf(sg*v0, sg*v1), fmaxf(sg*v2, sg*v3));
        m = fmaxf(m, __shfl_xor(m, 16, 64));
        m = fmaxf(m, __shfl_xor(m, 32, 64));
        if (lane < 16) wext[rowbase + nt*16 + ln] = sg*m;   // dense 64B line
      }
    } else {
      // edge windows (wyg==31 or wxg==31): stats only, masked to 126x126
      const bool yv = (wyg*4 + q) < OH;
      #pragma unroll
      for (int nt = 0; nt < 4; ++nt) {
        #pragma unroll
        for (int r = 0; r < 4; ++r) {
          const bool okp = yv && (wxg*4 + r < OW);
          const float v = okp ? acc[nt][r] : 0.f;
          s[nt] += v; sq[nt] += v*v;
        }
      }
    }
  }

  // per-wave stat reduce: quads (xor 16,32) then channels-in-group (xor 1,2)
  #pragma unroll
  for (int nt = 0; nt < 4; ++nt) {
    float a = s[nt], c2 = sq[nt];
    a  += __shfl_xor(a, 16, 64);  a  += __shfl_xor(a, 32, 64);
    a  += __shfl_xor(a, 1, 64);   a  += __shfl_xor(a, 2, 64);
    c2 += __shfl_xor(c2, 16, 64); c2 += __shfl_xor(c2, 32, 64);
    c2 += __shfl_xor(c2, 1, 64);  c2 += __shfl_xor(c2, 2, 64);
    if (lane < 16 && (lane & 3) == 0) {
      red[wave][nt*4 + (ln >> 2)][0] = a;
      red[wave][nt*4 + (ln >> 2)][1] = c2;
    }
  }
  __syncthreads();
  if (tid < 32) {
    const int g = tid >> 1, k = tid & 1;
    const float t = red[0][g][k] + red[1][g][k] + red[2][g][k] + red[3][g][k];
    ws[OFF_PART + (((size_t)b*NGROUPS + g)*16 + tileIdx)*2 + k] = t;
  }
}

// Fused stats-finalize + affine + clamp + NCHW transpose.
// One block per (b, wy); partials (4KB/batch) are L2-hot, redundant reduce is free.
__global__ __launch_bounds__(256)
void finalize_kernel(const float* __restrict__ gnw,
                     const float* __restrict__ gnb,
                     const float* __restrict__ scale,
                     const float* __restrict__ ws,
                     float* __restrict__ out)
{
  __shared__ float stat[NGROUPS][2];
  __shared__ float As[COUT], Bs[COUT];
  __shared__ float vout[COUT*PWN];   // [c][wx], stride 31 -> conflict-free

  const int tid = threadIdx.x;
  const int wy  = blockIdx.x;   // 0..30
  const int b   = blockIdx.y;

  if (tid < NGROUPS) {
    const float* p = ws + OFF_PART + ((size_t)(b*NGROUPS + tid))*32;
    float s = 0.f, sq = 0.f;
    #pragma unroll
    for (int t = 0; t < 16; ++t) { s += p[t*2]; sq += p[t*2+1]; }
    const float N = (float)(CPG * OH * OW);
    const float mean = s / N;
    const float var  = sq / N - mean*mean;
    stat[tid][0] = mean;
    stat[tid][1] = rsqrtf(var + 1e-5f);
  }
  __syncthreads();
  if (tid < COUT) {
    const int c = tid, g = c >> 2;
    const float ag = stat[g][1] * gnw[c];
    As[c] = ag * scale[c];
    Bs[c] = (gnb[c] - stat[g][0] * ag) * scale[c];
  }
  __syncthreads();

  const size_t rb = (size_t)(b*PWN + wy)*PWN*COUT;
  for (int idx = tid; idx < PWN*COUT; idx += 256) {
    const int c = idx & 63, wx = idx >> 6;
    const float ext = ws[OFF_WEXT + rb + idx];
    float v = fmaf(As[c], ext, Bs[c]);
    v = fminf(fmaxf(v, 0.f), 1.f);
    vout[c*PWN + wx] = v;
  }
  __syncthreads();

  for (int idx = tid; idx < COUT*PWN; idx += 256) {
    const int c = idx / PWN, wx = idx - c*PWN;
    out[(((size_t)b*COUT + c)*PWN + wy)*PWN + wx] = vout[idx];
  }
}

extern "C" void kernel_launch(void* const* d_in, const int* in_sizes, int n_in,
                              void* d_out, int out_size, void* d_ws, size_t ws_size,
                              hipStream_t stream)
{
  const float* x     = (const float*)d_in[0];
  const float* cw    = (const float*)d_in[1];
  const float* cb    = (const float*)d_in[2];
  const float* gnw   = (const float*)d_in[3];
  const float* gnb   = (const float*)d_in[4];
  const float* scale = (const float*)d_in[5];
  float* out = (float*)d_out;
  float* ws  = (float*)d_ws;

  dim3 gridA(16, NB, 1);
  conv_mfma_kernel<<<gridA, 256, 0, stream>>>(x, cw, cb, gnw, scale, ws);

  dim3 gridF(PWN, NB, 1);
  finalize_kernel<<<gridF, 256, 0, stream>>>(gnw, gnb, scale, ws, out);
}

// Round 8
// 194.289 us; speedup vs baseline: 2.1460x; 1.0084x over previous
//
#include <hip/hip_runtime.h>
#include <math.h>

typedef _Float16 f16x8 __attribute__((ext_vector_type(8)));
typedef float f32x4 __attribute__((ext_vector_type(4)));

#define CIN 8
#define HIN 128
#define WIN 128
#define OH 126
#define OW 126
#define COUT 64
#define NB 128
#define NGROUPS 16
#define CPG 4
#define PWN 31
#define XROWS 35   // max row touched: base(28)+dy(3)+ky(3)=34

// workspace layout
// Extremum plane stored as f16 [b][wy][wx][c] (c innermost, element units).
// ONLY change vs the known-good R5 kernel (f32 plane). R6/R7's common failing
// novelty was the 16x16-tile geometry; this round reverts it entirely.
#define NPOOL (NB*PWN*PWN*COUT)          // 7,872,512 f16 elements
#define OFF_PART (NPOOL/2)               // float offset; [b][g][tile16][{sum,sumsq}]
#define NPART (NB*NGROUPS*16*2)          // 65,536 floats

// Conv via MFMA implicit GEMM (R5-proven structure).
// K ordering: k = khw*8 + ci  (khw = ky*3+kx, padded 9..11 with W=0)
// LDS x tile: [row 35][col 34][ci 8] f16 ; one ds_write_b128 per pixel
// LDS w:      [khw 12][n 64][ci 8] f16
// M-tile = one 4x4 pool window: C layout col=lane&15=channel, row=q*4+reg.
// Bias folded into MFMA C operand. Single signed extremum per channel
// (sign of gnw*scale known pre-stats since inv_std>0).
__global__ __launch_bounds__(256, 4)
void conv_mfma_kernel(const float* __restrict__ x,
                      const float* __restrict__ w,
                      const float* __restrict__ bias,
                      const float* __restrict__ gnw,
                      const float* __restrict__ scale,
                      float* __restrict__ ws)
{
  __shared__ __align__(16) _Float16 xs[XROWS*34*8];   // 19,040 B
  __shared__ __align__(16) _Float16 wls[12*64*8];     // 12,288 B
  __shared__ float red[4][16][2];

  const int tid  = threadIdx.x;
  const int lane = tid & 63, wave = tid >> 6;
  const int tileIdx = blockIdx.x;          // 0..15
  const int tx = tileIdx & 3, ty = tileIdx >> 2;
  const int b  = blockIdx.y;
  const int ox0 = tx*32, oy0 = ty*32;

  // ---- stage weights [khw][n][ci], khw>=9 zeroed ----
  for (int idx = tid; idx < 12*64*8; idx += 256) {
    const int ci = idx & 7, n = (idx >> 3) & 63, khw = idx >> 9;
    const float v = (khw < 9) ? w[(n*CIN + ci)*9 + khw] : 0.f;
    wls[idx] = (_Float16)v;
  }

  // ---- stage x tile: pack 8 ci -> one b128 write per pixel (conflict-free) ----
  const float* xb = x + (size_t)b * CIN*HIN*WIN;
  for (int p = tid; p < XROWS*34; p += 256) {
    const int r = p / 34, c = p - r*34;
    const int iy = oy0 + r, ix = ox0 + c;
    const bool ok = (iy < HIN) && (ix < WIN);
    const int gbase = iy*WIN + ix;
    f16x8 pk;
    #pragma unroll
    for (int ci = 0; ci < 8; ++ci) {
      const float v = ok ? xb[ci*HIN*WIN + gbase] : 0.f;
      pk[ci] = (_Float16)v;
    }
    *(f16x8*)&xs[p*8] = pk;
  }
  __syncthreads();

  const int q = lane >> 4, ln = lane & 15;

  // B fragments: 4 ch-tiles x 3 K-chunks resident (48 VGPRs)
  f16x8 bf[4][3];
  #pragma unroll
  for (int nt = 0; nt < 4; ++nt)
    #pragma unroll
    for (int c = 0; c < 3; ++c)
      bf[nt][c] = *(const f16x8*)&wls[((c*4 + q)*64 + nt*16 + ln)*8];

  // per-lane A offsets (A lane map: m = lane&15 pixel, k-quad = lane>>4)
  const int dy = ln >> 2, dx = ln & 3;
  int aoff[3];
  #pragma unroll
  for (int c = 0; c < 3; ++c) {
    const int khw = c*4 + q;
    const int ky = khw / 3, kx = khw - 3*(khw/3);
    aoff[c] = ((dy + ky)*34 + (dx + kx))*8;
  }

  float bias_r[4], sgn[4];
  #pragma unroll
  for (int nt = 0; nt < 4; ++nt) {
    const int c = nt*16 + ln;
    bias_r[nt] = bias[c];
    sgn[nt] = (gnw[c]*scale[c] >= 0.f) ? 1.f : -1.f;  // GN slope sign (inv>0)
  }

  float s[4]  = {0.f,0.f,0.f,0.f};
  float sq[4] = {0.f,0.f,0.f,0.f};
  _Float16* wext = (_Float16*)ws;

  // 16 pool windows per wave (2 window-rows x 8 cols)
  #pragma unroll 2
  for (int i = 0; i < 16; ++i) {
    const int wyl = wave*2 + (i >> 3), wxl = i & 7;
    const int base = (wyl*4*34 + wxl*4)*8;

    f32x4 acc[4];
    #pragma unroll
    for (int nt = 0; nt < 4; ++nt) {
      const float bv = bias_r[nt];
      acc[nt] = (f32x4){bv, bv, bv, bv};   // bias as MFMA C operand
    }
    #pragma unroll
    for (int c = 0; c < 3; ++c) {
      const f16x8 a = *(const f16x8*)&xs[base + aoff[c]];
      #pragma unroll
      for (int nt = 0; nt < 4; ++nt)
        acc[nt] = __builtin_amdgcn_mfma_f32_16x16x32_f16(a, bf[nt][c], acc[nt], 0, 0, 0);
    }

    const int wyg = ty*8 + wyl, wxg = tx*8 + wxl;
    if ((wyg < PWN) && (wxg < PWN)) {
      const size_t rowbase = ((size_t)(b*PWN + wyg)*PWN + wxg)*COUT;
      #pragma unroll
      for (int nt = 0; nt < 4; ++nt) {
        const float v0 = acc[nt][0], v1 = acc[nt][1];
        const float v2 = acc[nt][2], v3 = acc[nt][3];
        s[nt]  += (v0+v1) + (v2+v3);
        sq[nt] += v0*v0 + v1*v1 + v2*v2 + v3*v3;
        const float sg = sgn[nt];
        float m = fmaxf(fmaxf(sg*v0, sg*v1), fmaxf(sg*v2, sg*v3));
        m = fmaxf(m, __shfl_xor(m, 16, 64));
        m = fmaxf(m, __shfl_xor(m, 32, 64));
        if (lane < 16) wext[rowbase + nt*16 + ln] = (_Float16)(sg*m);
      }
    } else {
      // edge windows (wyg==31 or wxg==31): stats only, masked to 126x126
      const bool yv = (wyg*4 + q) < OH;
      #pragma unroll
      for (int nt = 0; nt < 4; ++nt) {
        #pragma unroll
        for (int r = 0; r < 4; ++r) {
          const bool okp = yv && (wxg*4 + r < OW);
          const float v = okp ? acc[nt][r] : 0.f;
          s[nt] += v; sq[nt] += v*v;
        }
      }
    }
  }

  // per-wave stat reduce: quads (xor 16,32) then channels-in-group (xor 1,2)
  #pragma unroll
  for (int nt = 0; nt < 4; ++nt) {
    float a = s[nt], c2 = sq[nt];
    a  += __shfl_xor(a, 16, 64);  a  += __shfl_xor(a, 32, 64);
    a  += __shfl_xor(a, 1, 64);   a  += __shfl_xor(a, 2, 64);
    c2 += __shfl_xor(c2, 16, 64); c2 += __shfl_xor(c2, 32, 64);
    c2 += __shfl_xor(c2, 1, 64);  c2 += __shfl_xor(c2, 2, 64);
    if (lane < 16 && (lane & 3) == 0) {
      red[wave][nt*4 + (ln >> 2)][0] = a;
      red[wave][nt*4 + (ln >> 2)][1] = c2;
    }
  }
  __syncthreads();
  if (tid < 32) {
    const int g = tid >> 1, k = tid & 1;
    const float t = red[0][g][k] + red[1][g][k] + red[2][g][k] + red[3][g][k];
    ws[OFF_PART + (((size_t)b*NGROUPS + g)*16 + tileIdx)*2 + k] = t;
  }
}

// Fused stats-finalize + affine + clamp + NCHW transpose (R5 structure,
// f16 extremum reads).
__global__ __launch_bounds__(256)
void finalize_kernel(const float* __restrict__ gnw,
                     const float* __restrict__ gnb,
                     const float* __restrict__ scale,
                     const float* __restrict__ ws,
                     float* __restrict__ out)
{
  __shared__ float stat[NGROUPS][2];
  __shared__ float As[COUT], Bs[COUT];
  __shared__ float vout[COUT*PWN];   // [c][wx], stride 31 -> conflict-free

  const int tid = threadIdx.x;
  const int wy  = blockIdx.x;   // 0..30
  const int b   = blockIdx.y;

  if (tid < NGROUPS) {
    const float* p = ws + OFF_PART + ((size_t)(b*NGROUPS + tid))*32;
    float s = 0.f, sq = 0.f;
    #pragma unroll
    for (int t = 0; t < 16; ++t) { s += p[t*2]; sq += p[t*2+1]; }
    const float N = (float)(CPG * OH * OW);
    const float mean = s / N;
    const float var  = sq / N - mean*mean;
    stat[tid][0] = mean;
    stat[tid][1] = rsqrtf(var + 1e-5f);
  }
  __syncthreads();
  if (tid < COUT) {
    const int c = tid, g = c >> 2;
    const float ag = stat[g][1] * gnw[c];
    As[c] = ag * scale[c];
    Bs[c] = (gnb[c] - stat[g][0] * ag) * scale[c];
  }
  __syncthreads();

  const _Float16* wext = (const _Float16*)ws;
  const size_t rb = (size_t)(b*PWN + wy)*PWN*COUT;
  for (int idx = tid; idx < PWN*COUT; idx += 256) {
    const int c = idx & 63, wx = idx >> 6;
    const float ext = (float)wext[rb + idx];
    float v = fmaf(As[c], ext, Bs[c]);
    v = fminf(fmaxf(v, 0.f), 1.f);
    vout[c*PWN + wx] = v;
  }
  __syncthreads();

  for (int idx = tid; idx < COUT*PWN; idx += 256) {
    const int c = idx / PWN, wx = idx - c*PWN;
    out[(((size_t)b*COUT + c)*PWN + wy)*PWN + wx] = vout[idx];
  }
}

extern "C" void kernel_launch(void* const* d_in, const int* in_sizes, int n_in,
                              void* d_out, int out_size, void* d_ws, size_t ws_size,
                              hipStream_t stream)
{
  const float* x     = (const float*)d_in[0];
  const float* cw    = (const float*)d_in[1];
  const float* cb    = (const float*)d_in[2];
  const float* gnw   = (const float*)d_in[3];
  const float* gnb   = (const float*)d_in[4];
  const float* scale = (const float*)d_in[5];
  float* out = (float*)d_out;
  float* ws  = (float*)d_ws;

  dim3 gridA(16, NB, 1);
  conv_mfma_kernel<<<gridA, 256, 0, stream>>>(x, cw, cb, gnw, scale, ws);

  dim3 gridF(PWN, NB, 1);
  finalize_kernel<<<gridF, 256, 0, stream>>>(gnw, gnb, scale, ws, out);
}